// Round 10
// baseline (315.626 us; speedup 1.0000x reference)
//
#include <hip/hip_runtime.h>

// MessagePassingNet on MI355X — Round 23: k1 scatter ILP=4.
//   R22: zero-fold -7 µs (total 307.5, 4 launches). Budget: edge 110 (floor),
//   k1 ~90, atom ~38, scan ~10. k1's scatter half = ILP-1 atomic chain:
//   edge load -> atomicAdd(cnt[d]) ret-val -> bucket write, ~1100 cy exposed.
//   Fix: 4 independent edges/thread (4 chains in flight, ~4x less exposed
//   latency; no regalloc risk — ~8 regs/chain). Scatter blocks 4096->1024,
//   grid 3072, 1:2 scatter:pre interleave (b%3==0 -> scatter). new_states
//   zero-fold rides along (8 float4/thread = 32 MB exactly).
//   Edge/atom/scan/k0 byte-frozen.

constexpr int N_ATOMS = 131072;
constexpr int N_EDGES = 1048576;
constexpr int DD      = 64;
constexpr int OUTD    = 16;
constexpr int SH      = 72;     // halfword row stride for hi/lo LDS tiles
constexpr int SY      = 68;     // float row stride for atom_pre staging
constexpr int BCAP    = 16;     // bucket capacity per atom (Poisson(8): ~900 ovf)

typedef __bf16 bf16x8 __attribute__((ext_vector_type(8)));
typedef float  f32x4  __attribute__((ext_vector_type(4)));
typedef unsigned short u16x8 __attribute__((ext_vector_type(8)));

#define DEV_INLINE __device__ __forceinline__

DEV_INLINE float relu(float x) { return x > 0.f ? x : 0.f; }

DEV_INLINE unsigned short bfbits(float x) {
  __bf16 h = (__bf16)x;
  return __builtin_bit_cast(unsigned short, h);
}
DEV_INLINE float bfval(unsigned short u) {
  unsigned int v = ((unsigned int)u) << 16;
  return __builtin_bit_cast(float, v);
}
DEV_INLINE f32x4 mfma16(bf16x8 a, bf16x8 b, f32x4 c) {
  return __builtin_amdgcn_mfma_f32_16x16x32_bf16(a, b, c, 0, 0, 0);
}
DEV_INLINE bf16x8 ldfrag(const unsigned short* p) { return *(const bf16x8*)p; }

DEV_INLINE void mk_frag(float4 a0, float4 a1, bf16x8& fh, bf16x8& fl) {
  const float v[8] = {a0.x, a0.y, a0.z, a0.w, a1.x, a1.y, a1.z, a1.w};
  u16x8 hh, ll;
#pragma unroll
  for (int i = 0; i < 8; ++i) {
    unsigned short h = bfbits(v[i]);
    hh[i] = h;
    ll[i] = bfbits(v[i] - bfval(h));
  }
  fh = __builtin_bit_cast(bf16x8, hh);
  fl = __builtin_bit_cast(bf16x8, ll);
}

// ---- shared atom_pre body: Yd = X*W0d + b0, Ys = X*W0s; LDS-staged stores
DEV_INLINE void atom_pre_body(const float* __restrict__ atom_states,
                              const unsigned short* __restrict__ whi,
                              const unsigned short* __restrict__ wlo,
                              const float* __restrict__ b0,
                              float* __restrict__ Yd, float* __restrict__ Ys,
                              int a0, int t, float* st)
{
  const int l  = t & 63;
  const int w  = t >> 6;
  const int fi = (l >> 4) * 2;
  const int cc = l & 15;
  const int arow = a0 + w * 16 + (l & 15);

  bf16x8 xh[2], xl[2];
  {
    const float4* px = (const float4*)(atom_states + (size_t)arow * DD);
#pragma unroll
    for (int s = 0; s < 2; ++s) {
      float4 x0 = px[s * 8 + fi], x1 = px[s * 8 + fi + 1];
      mk_frag(x0, x1, xh[s], xl[s]);
    }
  }

#pragma unroll
  for (int side = 0; side < 2; ++side) {
    f32x4 acc[4];
#pragma unroll
    for (int j = 0; j < 4; ++j) acc[j] = (f32x4){0.f, 0.f, 0.f, 0.f};
#pragma unroll
    for (int s = 0; s < 2; ++s) {
#pragma unroll
      for (int j = 0; j < 4; ++j) {
        const int fo = side * 4096 + ((j * 2 + s) * 64 + l) * 8;
        bf16x8 bh = ldfrag(whi + fo);
        bf16x8 bl = ldfrag(wlo + fo);
        acc[j] = mfma16(xl[s], bh, acc[j]);
        acc[j] = mfma16(xh[s], bl, acc[j]);
        acc[j] = mfma16(xh[s], bh, acc[j]);
      }
    }
#pragma unroll
    for (int j = 0; j < 4; ++j) {
      const int   c  = j * 16 + cc;
      const float bb = side ? 0.f : b0[c];
#pragma unroll
      for (int i = 0; i < 4; ++i) {
        const int r = (l >> 4) * 4 + i;
        st[r * SY + c] = acc[j][i] + bb;
      }
    }
    {
      float* Y = side ? Ys : Yd;
      const int rr = l >> 2;
      const int c0 = (l & 3) * 16;
      float4* dst = (float4*)(Y + (size_t)(a0 + w * 16 + rr) * DD + c0);
      const float4* src = (const float4*)&st[rr * SY + c0];
#pragma unroll
      for (int f = 0; f < 4; ++f) dst[f] = src[f];
    }
  }
}

// ===========================================================================
// k0_pack_zero: blocks [0,12) weight pack; [12,140) zero cnt; block 12 t==0
// zeros ovf_cnt+gbase. Replaces 2 memset launches.
// ===========================================================================
__global__ __launch_bounds__(256)
void k0_pack_zero(const float* __restrict__ w0, const float* __restrict__ w1,
                  const float* __restrict__ w2, const float* __restrict__ f1,
                  const float* __restrict__ f2,
                  unsigned short* __restrict__ whi, unsigned short* __restrict__ wlo,
                  int* __restrict__ cnt, int* __restrict__ flags)
{
  const int t = threadIdx.x, b = blockIdx.x;
  if (b >= 12) {
    const int bi = b - 12;                         // 0..127
    ((int4*)cnt)[bi * 256 + t] = make_int4(0, 0, 0, 0);
    if (bi == 0 && t == 0) { flags[0] = 0; flags[1] = 0; }
    return;
  }
  int tid = b * 256 + t;                           // 0..3071
  int sec = tid >> 9, rel = tid & 511;
  const float* w; int rowoff = 0;
  switch (sec) {
    case 0: w = w0; rowoff = 0;  break;
    case 1: w = w0; rowoff = 64; break;
    case 2: w = w1; break;
    case 3: w = w2; break;
    case 4: w = f1; break;
    default: w = f2; break;
  }
  const int tile = rel >> 6, lane = rel & 63;
  const int j = tile >> 1, s = tile & 1;
  const int n  = j * 16 + (lane & 15);
  const int kb = s * 32 + (lane >> 4) * 8;
  const int out = sec * 4096 + (tile * 64 + lane) * 8;
#pragma unroll
  for (int i = 0; i < 8; ++i) {
    float v = w[(rowoff + kb + i) * 64 + n];
    unsigned short h = bfbits(v);
    whi[out + i] = h;
    wlo[out + i] = bfbits(v - bfval(h));
  }
}

// ===========================================================================
// Path C: k1 = bucket scatter ILP=4 (1 of 3 blocks) || atom_pre (2 of 3).
// Scatter: 1024 blocks x 256 t x 4 edges; 4 independent atomic chains in
// flight per thread. Also zeroes new_states (8 float4/thread = 32 MB).
// Overflow edges go directly to ds_sorted tail.
// ===========================================================================
__global__ __launch_bounds__(256, 4)
void k1_bucket_pre(const float* __restrict__ atom_states,
                   const int* __restrict__ edge_src,
                   const int* __restrict__ edge_dst,
                   int* __restrict__ cnt, int* __restrict__ bucket,
                   int2* __restrict__ ds_sorted, int* __restrict__ ovf_cnt,
                   const unsigned short* __restrict__ whi,
                   const unsigned short* __restrict__ wlo,
                   const float* __restrict__ b0,
                   float* __restrict__ Yd, float* __restrict__ Ys,
                   float* __restrict__ new_states)
{
  __shared__ float Ystage[4][16 * SY];
  const int t = threadIdx.x, b = blockIdx.x;
  const int r3 = b % 3;
  if (r3 == 0) {
    const int sb = b / 3;                          // 0..1023
    // zero new_states: 1024 blocks x 256 t x 8 float4 = 32 MiB exactly
    float4* ns4 = (float4*)new_states;
#pragma unroll
    for (int k = 0; k < 8; ++k)
      ns4[sb * 2048 + k * 256 + t] = make_float4(0.f, 0.f, 0.f, 0.f);

    const int base = sb * 1024;
    int dv[4], sv[4];
#pragma unroll
    for (int k = 0; k < 4; ++k) {
      dv[k] = edge_dst[base + k * 256 + t];
      sv[k] = edge_src[base + k * 256 + t];
    }
#pragma unroll
    for (int k = 0; k < 4; ++k) {
      int pos = atomicAdd(&cnt[dv[k]], 1);
      if (pos < BCAP) {
        bucket[dv[k] * BCAP + pos] = sv[k];
      } else {
        int op = atomicAdd(ovf_cnt, 1);
        ds_sorted[N_EDGES - 1 - op] = make_int2(dv[k], sv[k]);
      }
    }
    return;
  }
  const int pb = (b / 3) * 2 + (r3 - 1);           // 0..2047
  atom_pre_body(atom_states, whi, wlo, b0, Yd, Ys, pb * 64, t,
                Ystage[t >> 6]);
}

// ===========================================================================
// Path B: hist only (cnt counts true degree)
// ===========================================================================
__global__ __launch_bounds__(256, 4)
void k1_hist(const int* __restrict__ edge_dst, int* __restrict__ cnt) {
  int i = blockIdx.x * 256 + threadIdx.x;
  atomicAdd(&cnt[edge_dst[i]], 1);
}

// ===========================================================================
// Path B: blocksum + scanwrite (cursor in memory for the atomic scatter)
// ===========================================================================
__global__ void blocksum_kernel(const int* __restrict__ cnt,
                                int* __restrict__ partial, int clampv) {
  __shared__ int s[256];
  int t = threadIdx.x;
  s[t] = min(cnt[blockIdx.x * 256 + t], clampv);
  __syncthreads();
  for (int off = 128; off > 0; off >>= 1) {
    if (t < off) s[t] += s[t + off];
    __syncthreads();
  }
  if (t == 0) partial[blockIdx.x] = s[0];
}

__global__ void scanwrite_kernel(const int* __restrict__ cnt,
                                 const int* __restrict__ partial,
                                 int* __restrict__ cursor, int clampv) {
  __shared__ int s[256];
  __shared__ int pS[256];
  int t = threadIdx.x, b = blockIdx.x;

  int acc = 0;
  int p0 = partial[t];       if (t < b)       acc += p0;
  int p1 = partial[256 + t]; if (256 + t < b) acc += p1;
  pS[t] = acc;
  __syncthreads();
  for (int off = 128; off > 0; off >>= 1) {
    if (t < off) pS[t] += pS[t + off];
    __syncthreads();
  }
  const int base = pS[0];

  int v = min(cnt[b * 256 + t], clampv);
  s[t] = v;
  __syncthreads();
  for (int off = 1; off < 256; off <<= 1) {
    int x = (t >= off) ? s[t - off] : 0;
    __syncthreads();
    s[t] += x;
    __syncthreads();
  }
  cursor[b * 256 + t] = base + s[t] - v;  // exclusive prefix of clamped cnt
}

// ===========================================================================
// Path C: scan+compact with ATOMIC base bump (block order irrelevant under
// all-atomic edge reduce). Single pass over cnt; no blocksum/partial.
// ===========================================================================
__global__ __launch_bounds__(256)
void scan_compact_atomic(const int* __restrict__ cnt,
                         int* __restrict__ gbase,
                         const int* __restrict__ bucket,
                         int2* __restrict__ ds_sorted) {
  __shared__ int s[256];
  __shared__ int curS[256];   // exclusive cursor per atom (block-local + base)
  __shared__ int vS[256];     // clamped count per atom
  __shared__ int baseS;
  int t = threadIdx.x, b = blockIdx.x;

  int v = min(cnt[b * 256 + t], BCAP);
  s[t] = v;
  __syncthreads();
  for (int off = 1; off < 256; off <<= 1) {
    int x = (t >= off) ? s[t - off] : 0;
    __syncthreads();
    s[t] += x;
    __syncthreads();
  }
  if (t == 255) baseS = atomicAdd(gbase, s[255]);  // block total
  __syncthreads();
  curS[t] = baseS + s[t] - v;
  vS[t]   = v;
  __syncthreads();

  // compact: 256 atoms x 16 slots = 4096 jobs, 16 per thread
#pragma unroll
  for (int h = 0; h < 16; ++h) {
    const int j = h * 256 + t;
    const int al = j >> 4;              // local atom 0..255
    const int slot = j & 15;
    if (slot < vS[al]) {
      const int a = b * 256 + al;
      ds_sorted[curS[al] + slot] = make_int2(a, bucket[a * BCAP + slot]);
    }
  }
}

// ===========================================================================
// Path B: scatter -> ds_sorted (2 of 3 blocks, also zeroes new_states) ||
// atom_pre (1 of 3 blocks)
// ===========================================================================
__global__ __launch_bounds__(256, 4)
void k2_scatter_pre(const float* __restrict__ atom_states,
                    const int* __restrict__ edge_src,
                    const int* __restrict__ edge_dst,
                    int* __restrict__ cursor, int2* __restrict__ ds_sorted,
                    const unsigned short* __restrict__ whi,
                    const unsigned short* __restrict__ wlo,
                    const float* __restrict__ b0,
                    float* __restrict__ Yd, float* __restrict__ Ys,
                    float* __restrict__ new_states)
{
  __shared__ float Ystage[4][16 * SY];
  const int t = threadIdx.x, b = blockIdx.x;
  const int r3 = b % 3;
  if (r3 < 2) {
    const int sb = (b / 3) * 2 + r3;
    float4* ns4 = (float4*)new_states;
    ns4[sb * 512 + t]       = make_float4(0.f, 0.f, 0.f, 0.f);
    ns4[sb * 512 + 256 + t] = make_float4(0.f, 0.f, 0.f, 0.f);

    int i = sb * 256 + t;
    int d = edge_dst[i];
    int pos = atomicAdd(&cursor[d], 1);
    ds_sorted[pos] = make_int2(d, edge_src[i]);
    return;
  }
  atom_pre_body(atom_states, whi, wlo, b0, Yd, Ys, (b / 3) * 64, t,
                Ystage[t >> 6]);
}

// ===========================================================================
// edge_kernel_v10: all-atomic segmented reduction, total == N_EDGES.
// [R20-proven ~110 µs — BYTE-FROZEN]
// ===========================================================================
__global__ __launch_bounds__(256, 4)
void edge_kernel_v10(const float* __restrict__ Yd,
                     const float* __restrict__ Ys,
                     const int2* __restrict__ ds_sorted,
                     const unsigned short* __restrict__ whi,
                     const unsigned short* __restrict__ wlo,
                     const float* __restrict__ b1,
                     const float* __restrict__ b2,
                     float* __restrict__ new_states)
{
  __shared__ __align__(16) unsigned short H2[4][2 * 32 * SH];

  const int t = threadIdx.x;
  const int w = t >> 6;
  const int l = t & 63;
  const int e0 = blockIdx.x * 128 + w * 32;

  unsigned short* h2 = H2[w];
  float* msg = (float*)H2[w];

  int d = 0, s = 0;
  if (l < 32) {
    int2 ds = ds_sorted[e0 + l];
    d = ds.x; s = ds.y;
  }

  const int m  = l & 15;
  const int fi = (l >> 4) * 2;
  const int cc = l & 15;

  bf16x8 a1h[2][2], a1l[2][2];
#pragma unroll
  for (int tile = 0; tile < 2; ++tile) {
    const int dm = __shfl(d, tile * 16 + m);
    const int sm = __shfl(s, tile * 16 + m);
    const float4* pd = (const float4*)(Yd + (size_t)dm * DD);
    const float4* ps = (const float4*)(Ys + (size_t)sm * DD);
#pragma unroll
    for (int s2 = 0; s2 < 2; ++s2) {
      float4 x0 = pd[s2 * 8 + fi], x1 = pd[s2 * 8 + fi + 1];
      float4 y0 = ps[s2 * 8 + fi], y1 = ps[s2 * 8 + fi + 1];
      float4 r0 = make_float4(relu(x0.x + y0.x), relu(x0.y + y0.y),
                              relu(x0.z + y0.z), relu(x0.w + y0.w));
      float4 r1 = make_float4(relu(x1.x + y1.x), relu(x1.y + y1.y),
                              relu(x1.z + y1.z), relu(x1.w + y1.w));
      mk_frag(r0, r1, a1h[tile][s2], a1l[tile][s2]);
    }
  }

  f32x4 acc[2][4];

#pragma unroll
  for (int tile = 0; tile < 2; ++tile)
#pragma unroll
    for (int j = 0; j < 4; ++j) acc[tile][j] = (f32x4){0.f, 0.f, 0.f, 0.f};
#pragma unroll
  for (int s2 = 0; s2 < 2; ++s2) {
#pragma unroll
    for (int j = 0; j < 4; ++j) {
      const int fo = 2 * 4096 + ((j * 2 + s2) * 64 + l) * 8;
      bf16x8 bh = ldfrag(whi + fo);
      bf16x8 bl = ldfrag(wlo + fo);
#pragma unroll
      for (int tile = 0; tile < 2; ++tile) {
        acc[tile][j] = mfma16(a1l[tile][s2], bh, acc[tile][j]);
        acc[tile][j] = mfma16(a1h[tile][s2], bl, acc[tile][j]);
        acc[tile][j] = mfma16(a1h[tile][s2], bh, acc[tile][j]);
      }
    }
  }
#pragma unroll
  for (int tile = 0; tile < 2; ++tile) {
#pragma unroll
    for (int j = 0; j < 4; ++j) {
      const int   c  = j * 16 + cc;
      const float bb = b1[c];
#pragma unroll
      for (int i = 0; i < 4; ++i) {
        const int r = tile * 16 + (l >> 4) * 4 + i;
        float v = relu(acc[tile][j][i] + bb);
        unsigned short hi = bfbits(v);
        h2[r * SH + c] = hi;
        h2[32 * SH + r * SH + c] = bfbits(v - bfval(hi));
      }
    }
  }

#pragma unroll
  for (int tile = 0; tile < 2; ++tile)
#pragma unroll
    for (int j = 0; j < 4; ++j) acc[tile][j] = (f32x4){0.f, 0.f, 0.f, 0.f};
  const int kq = (l >> 4) * 8;
#pragma unroll
  for (int s2 = 0; s2 < 2; ++s2) {
    bf16x8 ah[2], al[2];
#pragma unroll
    for (int tile = 0; tile < 2; ++tile) {
      const int mrow = tile * 16 + m;
      ah[tile] = ldfrag(&h2[mrow * SH + s2 * 32 + kq]);
      al[tile] = ldfrag(&h2[32 * SH + mrow * SH + s2 * 32 + kq]);
    }
#pragma unroll
    for (int j = 0; j < 4; ++j) {
      const int fo = 3 * 4096 + ((j * 2 + s2) * 64 + l) * 8;
      bf16x8 bh = ldfrag(whi + fo);
      bf16x8 bl = ldfrag(wlo + fo);
#pragma unroll
      for (int tile = 0; tile < 2; ++tile) {
        acc[tile][j] = mfma16(al[tile], bh, acc[tile][j]);
        acc[tile][j] = mfma16(ah[tile], bl, acc[tile][j]);
        acc[tile][j] = mfma16(ah[tile], bh, acc[tile][j]);
      }
    }
  }
#pragma unroll
  for (int tile = 0; tile < 2; ++tile) {
#pragma unroll
    for (int j = 0; j < 4; ++j) {
      const int   c  = j * 16 + cc;
      const float bb = b2[c];
#pragma unroll
      for (int i = 0; i < 4; ++i) {
        const int r = tile * 16 + (l >> 4) * 4 + i;
        msg[r * SH + c] = relu(acc[tile][j][i] + bb);
      }
    }
  }

  // ---- all-atomic segmented reduction over 32 rows
  {
    int   cur = __builtin_amdgcn_readlane(d, 0);
    float run = 0.f;
#pragma unroll
    for (int r = 0; r < 32; ++r) {
      float v  = msg[r * SH + l];
      int   dr = __builtin_amdgcn_readlane(d, r);
      if (r > 0 && dr != cur) {
        atomicAdd(new_states + (size_t)cur * DD + l, run);
        run = 0.f;
        cur = dr;
      }
      run += v;
    }
    atomicAdd(new_states + (size_t)cur * DD + l, run);
  }
}

// ===========================================================================
// atom_kernel_v2 (proven): readout MFMA + fp32 out + mol sum.
// ===========================================================================
__global__ __launch_bounds__(256, 4)
void atom_kernel_v2(const float* __restrict__ ns,
                    const unsigned short* __restrict__ whi,
                    const unsigned short* __restrict__ wlo,
                    const float* __restrict__ f1b,
                    const float* __restrict__ f2b,
                    const float* __restrict__ wo,
                    const float* __restrict__ bo,
                    float* __restrict__ out)
{
  __shared__ __align__(16) unsigned short Xb[2 * 64 * SH];
  __shared__ __align__(16) unsigned short Hb[2 * 64 * SH];
  unsigned short* Xh = Xb;
  unsigned short* Xl = Xb + 64 * SH;
  unsigned short* Hh = Hb;
  unsigned short* Hl = Hb + 64 * SH;
  float* h2f = (float*)Xb;
  float* oS  = (float*)Hb;

  const int t  = threadIdx.x;
  const int a0 = blockIdx.x * 64;

  {
    const int r  = t >> 2;
    const int k0 = (t & 3) * 16;
    const float4* s4 = (const float4*)(ns + (size_t)(a0 + r) * DD + k0);
#pragma unroll
    for (int f = 0; f < 4; ++f) {
      float4 v = s4[f];
      ushort4 h, lo;
      h.x = bfbits(v.x); lo.x = bfbits(v.x - bfval(h.x));
      h.y = bfbits(v.y); lo.y = bfbits(v.y - bfval(h.y));
      h.z = bfbits(v.z); lo.z = bfbits(v.z - bfval(h.z));
      h.w = bfbits(v.w); lo.w = bfbits(v.w - bfval(h.w));
      *(ushort4*)&Xh[r * SH + k0 + f * 4] = h;
      *(ushort4*)&Xl[r * SH + k0 + f * 4] = lo;
    }
  }

  const int l    = t & 63;
  const int w    = t >> 6;
  const int mrow = w * 16 + (l & 15);
  const int kq   = (l >> 4) * 8;
  const int cc   = l & 15;

  f32x4 acc[4];

#pragma unroll
  for (int j = 0; j < 4; ++j) acc[j] = (f32x4){0.f, 0.f, 0.f, 0.f};
#pragma unroll
  for (int s = 0; s < 2; ++s) {
    bf16x8 ah = ldfrag(&Xh[mrow * SH + s * 32 + kq]);
    bf16x8 al = ldfrag(&Xl[mrow * SH + s * 32 + kq]);
#pragma unroll
    for (int j = 0; j < 4; ++j) {
      const int fo = 4 * 4096 + ((j * 2 + s) * 64 + l) * 8;
      bf16x8 bh = ldfrag(whi + fo);
      bf16x8 bl = ldfrag(wlo + fo);
      acc[j] = mfma16(al, bh, acc[j]);
      acc[j] = mfma16(ah, bl, acc[j]);
      acc[j] = mfma16(ah, bh, acc[j]);
    }
  }
#pragma unroll
  for (int j = 0; j < 4; ++j) {
    const int   c  = j * 16 + cc;
    const float bb = f1b[c];
#pragma unroll
    for (int i = 0; i < 4; ++i) {
      const int r = w * 16 + (l >> 4) * 4 + i;
      float v = relu(acc[j][i] + bb);
      unsigned short hi = bfbits(v);
      Hh[r * SH + c] = hi;
      Hl[r * SH + c] = bfbits(v - bfval(hi));
    }
  }
  __syncthreads();

#pragma unroll
  for (int j = 0; j < 4; ++j) acc[j] = (f32x4){0.f, 0.f, 0.f, 0.f};
#pragma unroll
  for (int s = 0; s < 2; ++s) {
    bf16x8 ah = ldfrag(&Hh[mrow * SH + s * 32 + kq]);
    bf16x8 al = ldfrag(&Hl[mrow * SH + s * 32 + kq]);
#pragma unroll
    for (int j = 0; j < 4; ++j) {
      const int fo = 5 * 4096 + ((j * 2 + s) * 64 + l) * 8;
      bf16x8 bh = ldfrag(whi + fo);
      bf16x8 bl = ldfrag(wlo + fo);
      acc[j] = mfma16(al, bh, acc[j]);
      acc[j] = mfma16(ah, bl, acc[j]);
      acc[j] = mfma16(ah, bh, acc[j]);
    }
  }
#pragma unroll
  for (int j = 0; j < 4; ++j) {
    const int   c  = j * 16 + cc;
    const float bb = f2b[c];
#pragma unroll
    for (int i = 0; i < 4; ++i) {
      const int r = w * 16 + (l >> 4) * 4 + i;
      h2f[r * SH + c] = relu(acc[j][i] + bb);
    }
  }
  __syncthreads();

  {
    const int r  = t >> 2;
    const int c4 = (t & 3) * 4;
    float o4[4] = {0.f, 0.f, 0.f, 0.f};
#pragma unroll 8
    for (int k = 0; k < 64; ++k) {
      const float a = h2f[r * SH + k];
      float4 bw = *(const float4*)&wo[k * OUTD + c4];
      o4[0] += a * bw.x; o4[1] += a * bw.y; o4[2] += a * bw.z; o4[3] += a * bw.w;
    }
#pragma unroll
    for (int j = 0; j < 4; ++j)
      oS[r * 17 + c4 + j] = relu(o4[j] + bo[c4 + j]);
  }
  __syncthreads();

  if (t < 32) {
    const int m = t >> 4;
    const int c = t & 15;
    float s = 0.f;
#pragma unroll
    for (int a = 0; a < 32; ++a) s += oS[(m * 32 + a) * 17 + c];
    out[(blockIdx.x * 2 + m) * OUTD + c] = s;
  }
}

// ===========================================================================
extern "C" void kernel_launch(void* const* d_in, const int* in_sizes, int n_in,
                              void* d_out, int out_size, void* d_ws, size_t ws_size,
                              hipStream_t stream) {
  const float* atom_states = (const float*)d_in[0];
  const int*   edge_src    = (const int*)d_in[1];
  const int*   edge_dst    = (const int*)d_in[2];
  const float* ms0_w = (const float*)d_in[4];
  const float* ms0_b = (const float*)d_in[5];
  const float* ms1_w = (const float*)d_in[6];
  const float* ms1_b = (const float*)d_in[7];
  const float* ms2_w = (const float*)d_in[8];
  const float* ms2_b = (const float*)d_in[9];
  const float* fc1_w = (const float*)d_in[10];
  const float* fc1_b = (const float*)d_in[11];
  const float* fc2_w = (const float*)d_in[12];
  const float* fc2_b = (const float*)d_in[13];
  const float* out_w = (const float*)d_in[14];
  const float* out_b = (const float*)d_in[15];

  char* ws = (char*)d_ws;
  float* new_states = (float*)ws;
  size_t off = (size_t)N_ATOMS * DD * sizeof(float);                    // 32 MiB
  int* cnt     = (int*)(ws + off); off += (size_t)N_ATOMS * 4;          // +512 KiB
  int* cursor  = (int*)(ws + off); off += (size_t)N_ATOMS * 4;          // +512 KiB
  int* partial = (int*)(ws + off); off += 4096;                         // B-path
  int* flags   = (int*)(ws + off); off += 4096;  // [0]=ovf_cnt [1]=gbase
  unsigned short* whi = (unsigned short*)(ws + off); off += 24576 * 2;
  unsigned short* wlo = (unsigned short*)(ws + off); off += 24576 * 2;
  float* Yd = (float*)(ws + off); off += (size_t)N_ATOMS * DD * sizeof(float);
  float* Ys = (float*)(ws + off); off += (size_t)N_ATOMS * DD * sizeof(float);
  int2* ds_sorted = (int2*)(ws + off); off += (size_t)N_EDGES * 8;      // +8 MiB
  const size_t needB = off;                                             // ~105 MiB
  int* bucket = (int*)(ws + off); off += (size_t)N_ATOMS * BCAP * 4;    // +8 MiB
  const size_t needC = off;                                             // ~113 MiB

  const int useC = (ws_size >= needC) ? 1 : 0;   // constant across calls

  int* ovf_cnt = flags;
  int* gbase   = flags + 1;

  k0_pack_zero<<<140, 256, 0, stream>>>(ms0_w, ms1_w, ms2_w, fc1_w, fc2_w,
                                        whi, wlo, cnt, flags);

  if (useC) {
    k1_bucket_pre<<<3072, 256, 0, stream>>>(atom_states, edge_src, edge_dst,
                                            cnt, bucket, ds_sorted, ovf_cnt,
                                            whi, wlo, ms0_b, Yd, Ys, new_states);
    scan_compact_atomic<<<512, 256, 0, stream>>>(cnt, gbase, bucket, ds_sorted);
  } else {
    k1_hist<<<4096, 256, 0, stream>>>(edge_dst, cnt);
    blocksum_kernel<<<512, 256, 0, stream>>>(cnt, partial, 0x7fffffff);
    scanwrite_kernel<<<512, 256, 0, stream>>>(cnt, partial, cursor, 0x7fffffff);
    k2_scatter_pre<<<6144, 256, 0, stream>>>(atom_states, edge_src, edge_dst,
                                             cursor, ds_sorted,
                                             whi, wlo, ms0_b, Yd, Ys, new_states);
  }

  edge_kernel_v10<<<N_EDGES / 128, 256, 0, stream>>>(
      Yd, Ys, ds_sorted, whi, wlo, ms1_b, ms2_b, new_states);

  atom_kernel_v2<<<N_ATOMS / 64, 256, 0, stream>>>(
      new_states, whi, wlo, fc1_b, fc2_b, out_w, out_b, (float*)d_out);
}

// Round 11
// 302.430 us; speedup vs baseline: 1.0436x; 1.0436x over previous
//
#include <hip/hip_runtime.h>

// MessagePassingNet on MI355X — Round 24: revert to R22 (proven best, 307.5).
//   R23 post-mortem: scatter ILP=4 REGRESSED (+8 µs). Two errors: (1) ~1M
//   scatter threads already hide atomic latency via TLP — the limiter is
//   atomic THROUGHPUT, not latency, so per-thread ILP buys nothing;
//   (2) each atomicAdd result feeds a branch containing another atomic ->
//   chains serialized anyway. Reverted byte-exact to R22.
//   Session state: edge 110 µs = latency floor (5 attacks: LDS shrink,
//   swizzle, 2x reg-pipeline spills, XCD swizzle — all null/regressed);
//   non-edge minimized to 4 launches, scatter throughput-bound, remaining
//   targets inside the ±8 µs run-to-run noise band. Expect ~307 ± 5.

constexpr int N_ATOMS = 131072;
constexpr int N_EDGES = 1048576;
constexpr int DD      = 64;
constexpr int OUTD    = 16;
constexpr int SH      = 72;     // halfword row stride for hi/lo LDS tiles
constexpr int SY      = 68;     // float row stride for atom_pre staging
constexpr int BCAP    = 16;     // bucket capacity per atom (Poisson(8): ~900 ovf)

typedef __bf16 bf16x8 __attribute__((ext_vector_type(8)));
typedef float  f32x4  __attribute__((ext_vector_type(4)));
typedef unsigned short u16x8 __attribute__((ext_vector_type(8)));

#define DEV_INLINE __device__ __forceinline__

DEV_INLINE float relu(float x) { return x > 0.f ? x : 0.f; }

DEV_INLINE unsigned short bfbits(float x) {
  __bf16 h = (__bf16)x;
  return __builtin_bit_cast(unsigned short, h);
}
DEV_INLINE float bfval(unsigned short u) {
  unsigned int v = ((unsigned int)u) << 16;
  return __builtin_bit_cast(float, v);
}
DEV_INLINE f32x4 mfma16(bf16x8 a, bf16x8 b, f32x4 c) {
  return __builtin_amdgcn_mfma_f32_16x16x32_bf16(a, b, c, 0, 0, 0);
}
DEV_INLINE bf16x8 ldfrag(const unsigned short* p) { return *(const bf16x8*)p; }

DEV_INLINE void mk_frag(float4 a0, float4 a1, bf16x8& fh, bf16x8& fl) {
  const float v[8] = {a0.x, a0.y, a0.z, a0.w, a1.x, a1.y, a1.z, a1.w};
  u16x8 hh, ll;
#pragma unroll
  for (int i = 0; i < 8; ++i) {
    unsigned short h = bfbits(v[i]);
    hh[i] = h;
    ll[i] = bfbits(v[i] - bfval(h));
  }
  fh = __builtin_bit_cast(bf16x8, hh);
  fl = __builtin_bit_cast(bf16x8, ll);
}

// ---- shared atom_pre body: Yd = X*W0d + b0, Ys = X*W0s; LDS-staged stores
DEV_INLINE void atom_pre_body(const float* __restrict__ atom_states,
                              const unsigned short* __restrict__ whi,
                              const unsigned short* __restrict__ wlo,
                              const float* __restrict__ b0,
                              float* __restrict__ Yd, float* __restrict__ Ys,
                              int a0, int t, float* st)
{
  const int l  = t & 63;
  const int w  = t >> 6;
  const int fi = (l >> 4) * 2;
  const int cc = l & 15;
  const int arow = a0 + w * 16 + (l & 15);

  bf16x8 xh[2], xl[2];
  {
    const float4* px = (const float4*)(atom_states + (size_t)arow * DD);
#pragma unroll
    for (int s = 0; s < 2; ++s) {
      float4 x0 = px[s * 8 + fi], x1 = px[s * 8 + fi + 1];
      mk_frag(x0, x1, xh[s], xl[s]);
    }
  }

#pragma unroll
  for (int side = 0; side < 2; ++side) {
    f32x4 acc[4];
#pragma unroll
    for (int j = 0; j < 4; ++j) acc[j] = (f32x4){0.f, 0.f, 0.f, 0.f};
#pragma unroll
    for (int s = 0; s < 2; ++s) {
#pragma unroll
      for (int j = 0; j < 4; ++j) {
        const int fo = side * 4096 + ((j * 2 + s) * 64 + l) * 8;
        bf16x8 bh = ldfrag(whi + fo);
        bf16x8 bl = ldfrag(wlo + fo);
        acc[j] = mfma16(xl[s], bh, acc[j]);
        acc[j] = mfma16(xh[s], bl, acc[j]);
        acc[j] = mfma16(xh[s], bh, acc[j]);
      }
    }
#pragma unroll
    for (int j = 0; j < 4; ++j) {
      const int   c  = j * 16 + cc;
      const float bb = side ? 0.f : b0[c];
#pragma unroll
      for (int i = 0; i < 4; ++i) {
        const int r = (l >> 4) * 4 + i;
        st[r * SY + c] = acc[j][i] + bb;
      }
    }
    {
      float* Y = side ? Ys : Yd;
      const int rr = l >> 2;
      const int c0 = (l & 3) * 16;
      float4* dst = (float4*)(Y + (size_t)(a0 + w * 16 + rr) * DD + c0);
      const float4* src = (const float4*)&st[rr * SY + c0];
#pragma unroll
      for (int f = 0; f < 4; ++f) dst[f] = src[f];
    }
  }
}

// ===========================================================================
// k0_pack_zero: blocks [0,12) weight pack; [12,140) zero cnt; block 12 t==0
// zeros ovf_cnt+gbase. Replaces 2 memset launches.
// ===========================================================================
__global__ __launch_bounds__(256)
void k0_pack_zero(const float* __restrict__ w0, const float* __restrict__ w1,
                  const float* __restrict__ w2, const float* __restrict__ f1,
                  const float* __restrict__ f2,
                  unsigned short* __restrict__ whi, unsigned short* __restrict__ wlo,
                  int* __restrict__ cnt, int* __restrict__ flags)
{
  const int t = threadIdx.x, b = blockIdx.x;
  if (b >= 12) {
    const int bi = b - 12;                         // 0..127
    ((int4*)cnt)[bi * 256 + t] = make_int4(0, 0, 0, 0);
    if (bi == 0 && t == 0) { flags[0] = 0; flags[1] = 0; }
    return;
  }
  int tid = b * 256 + t;                           // 0..3071
  int sec = tid >> 9, rel = tid & 511;
  const float* w; int rowoff = 0;
  switch (sec) {
    case 0: w = w0; rowoff = 0;  break;
    case 1: w = w0; rowoff = 64; break;
    case 2: w = w1; break;
    case 3: w = w2; break;
    case 4: w = f1; break;
    default: w = f2; break;
  }
  const int tile = rel >> 6, lane = rel & 63;
  const int j = tile >> 1, s = tile & 1;
  const int n  = j * 16 + (lane & 15);
  const int kb = s * 32 + (lane >> 4) * 8;
  const int out = sec * 4096 + (tile * 64 + lane) * 8;
#pragma unroll
  for (int i = 0; i < 8; ++i) {
    float v = w[(rowoff + kb + i) * 64 + n];
    unsigned short h = bfbits(v);
    whi[out + i] = h;
    wlo[out + i] = bfbits(v - bfval(h));
  }
}

// ===========================================================================
// Path C: k1 = bucket scatter (2 of 3 blocks) || atom_pre (1 of 3 blocks).
// Scatter blocks ALSO zero new_states (2 float4/thread; 4096 blocks cover
// 32 MB exactly) — rides free under atomic latency. Overflow edges go
// directly to ds_sorted tail.
// ===========================================================================
__global__ __launch_bounds__(256, 4)
void k1_bucket_pre(const float* __restrict__ atom_states,
                   const int* __restrict__ edge_src,
                   const int* __restrict__ edge_dst,
                   int* __restrict__ cnt, int* __restrict__ bucket,
                   int2* __restrict__ ds_sorted, int* __restrict__ ovf_cnt,
                   const unsigned short* __restrict__ whi,
                   const unsigned short* __restrict__ wlo,
                   const float* __restrict__ b0,
                   float* __restrict__ Yd, float* __restrict__ Ys,
                   float* __restrict__ new_states)
{
  __shared__ float Ystage[4][16 * SY];
  const int t = threadIdx.x, b = blockIdx.x;
  const int r3 = b % 3;
  if (r3 < 2) {
    const int sb = (b / 3) * 2 + r3;               // 0..4095
    // zero new_states: 4096 blocks x 256 t x 2 float4 = 32 MiB exactly
    float4* ns4 = (float4*)new_states;
    ns4[sb * 512 + t]       = make_float4(0.f, 0.f, 0.f, 0.f);
    ns4[sb * 512 + 256 + t] = make_float4(0.f, 0.f, 0.f, 0.f);

    int i = sb * 256 + t;
    int d = edge_dst[i];
    int pos = atomicAdd(&cnt[d], 1);
    if (pos < BCAP) {
      bucket[d * BCAP + pos] = edge_src[i];
    } else {
      int op = atomicAdd(ovf_cnt, 1);
      ds_sorted[N_EDGES - 1 - op] = make_int2(d, edge_src[i]);
    }
    return;
  }
  atom_pre_body(atom_states, whi, wlo, b0, Yd, Ys, (b / 3) * 64, t,
                Ystage[t >> 6]);
}

// ===========================================================================
// Path B: hist only (cnt counts true degree)
// ===========================================================================
__global__ __launch_bounds__(256, 4)
void k1_hist(const int* __restrict__ edge_dst, int* __restrict__ cnt) {
  int i = blockIdx.x * 256 + threadIdx.x;
  atomicAdd(&cnt[edge_dst[i]], 1);
}

// ===========================================================================
// Path B: blocksum + scanwrite (cursor in memory for the atomic scatter)
// ===========================================================================
__global__ void blocksum_kernel(const int* __restrict__ cnt,
                                int* __restrict__ partial, int clampv) {
  __shared__ int s[256];
  int t = threadIdx.x;
  s[t] = min(cnt[blockIdx.x * 256 + t], clampv);
  __syncthreads();
  for (int off = 128; off > 0; off >>= 1) {
    if (t < off) s[t] += s[t + off];
    __syncthreads();
  }
  if (t == 0) partial[blockIdx.x] = s[0];
}

__global__ void scanwrite_kernel(const int* __restrict__ cnt,
                                 const int* __restrict__ partial,
                                 int* __restrict__ cursor, int clampv) {
  __shared__ int s[256];
  __shared__ int pS[256];
  int t = threadIdx.x, b = blockIdx.x;

  int acc = 0;
  int p0 = partial[t];       if (t < b)       acc += p0;
  int p1 = partial[256 + t]; if (256 + t < b) acc += p1;
  pS[t] = acc;
  __syncthreads();
  for (int off = 128; off > 0; off >>= 1) {
    if (t < off) pS[t] += pS[t + off];
    __syncthreads();
  }
  const int base = pS[0];

  int v = min(cnt[b * 256 + t], clampv);
  s[t] = v;
  __syncthreads();
  for (int off = 1; off < 256; off <<= 1) {
    int x = (t >= off) ? s[t - off] : 0;
    __syncthreads();
    s[t] += x;
    __syncthreads();
  }
  cursor[b * 256 + t] = base + s[t] - v;  // exclusive prefix of clamped cnt
}

// ===========================================================================
// Path C: scan+compact with ATOMIC base bump (block order irrelevant under
// all-atomic edge reduce). Single pass over cnt; no blocksum/partial.
// ===========================================================================
__global__ __launch_bounds__(256)
void scan_compact_atomic(const int* __restrict__ cnt,
                         int* __restrict__ gbase,
                         const int* __restrict__ bucket,
                         int2* __restrict__ ds_sorted) {
  __shared__ int s[256];
  __shared__ int curS[256];   // exclusive cursor per atom (block-local + base)
  __shared__ int vS[256];     // clamped count per atom
  __shared__ int baseS;
  int t = threadIdx.x, b = blockIdx.x;

  int v = min(cnt[b * 256 + t], BCAP);
  s[t] = v;
  __syncthreads();
  for (int off = 1; off < 256; off <<= 1) {
    int x = (t >= off) ? s[t - off] : 0;
    __syncthreads();
    s[t] += x;
    __syncthreads();
  }
  if (t == 255) baseS = atomicAdd(gbase, s[255]);  // block total
  __syncthreads();
  curS[t] = baseS + s[t] - v;
  vS[t]   = v;
  __syncthreads();

  // compact: 256 atoms x 16 slots = 4096 jobs, 16 per thread
#pragma unroll
  for (int h = 0; h < 16; ++h) {
    const int j = h * 256 + t;
    const int al = j >> 4;              // local atom 0..255
    const int slot = j & 15;
    if (slot < vS[al]) {
      const int a = b * 256 + al;
      ds_sorted[curS[al] + slot] = make_int2(a, bucket[a * BCAP + slot]);
    }
  }
}

// ===========================================================================
// Path B: scatter -> ds_sorted (2 of 3 blocks, also zeroes new_states) ||
// atom_pre (1 of 3 blocks)
// ===========================================================================
__global__ __launch_bounds__(256, 4)
void k2_scatter_pre(const float* __restrict__ atom_states,
                    const int* __restrict__ edge_src,
                    const int* __restrict__ edge_dst,
                    int* __restrict__ cursor, int2* __restrict__ ds_sorted,
                    const unsigned short* __restrict__ whi,
                    const unsigned short* __restrict__ wlo,
                    const float* __restrict__ b0,
                    float* __restrict__ Yd, float* __restrict__ Ys,
                    float* __restrict__ new_states)
{
  __shared__ float Ystage[4][16 * SY];
  const int t = threadIdx.x, b = blockIdx.x;
  const int r3 = b % 3;
  if (r3 < 2) {
    const int sb = (b / 3) * 2 + r3;
    float4* ns4 = (float4*)new_states;
    ns4[sb * 512 + t]       = make_float4(0.f, 0.f, 0.f, 0.f);
    ns4[sb * 512 + 256 + t] = make_float4(0.f, 0.f, 0.f, 0.f);

    int i = sb * 256 + t;
    int d = edge_dst[i];
    int pos = atomicAdd(&cursor[d], 1);
    ds_sorted[pos] = make_int2(d, edge_src[i]);
    return;
  }
  atom_pre_body(atom_states, whi, wlo, b0, Yd, Ys, (b / 3) * 64, t,
                Ystage[t >> 6]);
}

// ===========================================================================
// edge_kernel_v10: all-atomic segmented reduction, total == N_EDGES.
// [proven ~110 µs — BYTE-FROZEN]
// ===========================================================================
__global__ __launch_bounds__(256, 4)
void edge_kernel_v10(const float* __restrict__ Yd,
                     const float* __restrict__ Ys,
                     const int2* __restrict__ ds_sorted,
                     const unsigned short* __restrict__ whi,
                     const unsigned short* __restrict__ wlo,
                     const float* __restrict__ b1,
                     const float* __restrict__ b2,
                     float* __restrict__ new_states)
{
  __shared__ __align__(16) unsigned short H2[4][2 * 32 * SH];

  const int t = threadIdx.x;
  const int w = t >> 6;
  const int l = t & 63;
  const int e0 = blockIdx.x * 128 + w * 32;

  unsigned short* h2 = H2[w];
  float* msg = (float*)H2[w];

  int d = 0, s = 0;
  if (l < 32) {
    int2 ds = ds_sorted[e0 + l];
    d = ds.x; s = ds.y;
  }

  const int m  = l & 15;
  const int fi = (l >> 4) * 2;
  const int cc = l & 15;

  bf16x8 a1h[2][2], a1l[2][2];
#pragma unroll
  for (int tile = 0; tile < 2; ++tile) {
    const int dm = __shfl(d, tile * 16 + m);
    const int sm = __shfl(s, tile * 16 + m);
    const float4* pd = (const float4*)(Yd + (size_t)dm * DD);
    const float4* ps = (const float4*)(Ys + (size_t)sm * DD);
#pragma unroll
    for (int s2 = 0; s2 < 2; ++s2) {
      float4 x0 = pd[s2 * 8 + fi], x1 = pd[s2 * 8 + fi + 1];
      float4 y0 = ps[s2 * 8 + fi], y1 = ps[s2 * 8 + fi + 1];
      float4 r0 = make_float4(relu(x0.x + y0.x), relu(x0.y + y0.y),
                              relu(x0.z + y0.z), relu(x0.w + y0.w));
      float4 r1 = make_float4(relu(x1.x + y1.x), relu(x1.y + y1.y),
                              relu(x1.z + y1.z), relu(x1.w + y1.w));
      mk_frag(r0, r1, a1h[tile][s2], a1l[tile][s2]);
    }
  }

  f32x4 acc[2][4];

#pragma unroll
  for (int tile = 0; tile < 2; ++tile)
#pragma unroll
    for (int j = 0; j < 4; ++j) acc[tile][j] = (f32x4){0.f, 0.f, 0.f, 0.f};
#pragma unroll
  for (int s2 = 0; s2 < 2; ++s2) {
#pragma unroll
    for (int j = 0; j < 4; ++j) {
      const int fo = 2 * 4096 + ((j * 2 + s2) * 64 + l) * 8;
      bf16x8 bh = ldfrag(whi + fo);
      bf16x8 bl = ldfrag(wlo + fo);
#pragma unroll
      for (int tile = 0; tile < 2; ++tile) {
        acc[tile][j] = mfma16(a1l[tile][s2], bh, acc[tile][j]);
        acc[tile][j] = mfma16(a1h[tile][s2], bl, acc[tile][j]);
        acc[tile][j] = mfma16(a1h[tile][s2], bh, acc[tile][j]);
      }
    }
  }
#pragma unroll
  for (int tile = 0; tile < 2; ++tile) {
#pragma unroll
    for (int j = 0; j < 4; ++j) {
      const int   c  = j * 16 + cc;
      const float bb = b1[c];
#pragma unroll
      for (int i = 0; i < 4; ++i) {
        const int r = tile * 16 + (l >> 4) * 4 + i;
        float v = relu(acc[tile][j][i] + bb);
        unsigned short hi = bfbits(v);
        h2[r * SH + c] = hi;
        h2[32 * SH + r * SH + c] = bfbits(v - bfval(hi));
      }
    }
  }

#pragma unroll
  for (int tile = 0; tile < 2; ++tile)
#pragma unroll
    for (int j = 0; j < 4; ++j) acc[tile][j] = (f32x4){0.f, 0.f, 0.f, 0.f};
  const int kq = (l >> 4) * 8;
#pragma unroll
  for (int s2 = 0; s2 < 2; ++s2) {
    bf16x8 ah[2], al[2];
#pragma unroll
    for (int tile = 0; tile < 2; ++tile) {
      const int mrow = tile * 16 + m;
      ah[tile] = ldfrag(&h2[mrow * SH + s2 * 32 + kq]);
      al[tile] = ldfrag(&h2[32 * SH + mrow * SH + s2 * 32 + kq]);
    }
#pragma unroll
    for (int j = 0; j < 4; ++j) {
      const int fo = 3 * 4096 + ((j * 2 + s2) * 64 + l) * 8;
      bf16x8 bh = ldfrag(whi + fo);
      bf16x8 bl = ldfrag(wlo + fo);
#pragma unroll
      for (int tile = 0; tile < 2; ++tile) {
        acc[tile][j] = mfma16(al[tile], bh, acc[tile][j]);
        acc[tile][j] = mfma16(ah[tile], bl, acc[tile][j]);
        acc[tile][j] = mfma16(ah[tile], bh, acc[tile][j]);
      }
    }
  }
#pragma unroll
  for (int tile = 0; tile < 2; ++tile) {
#pragma unroll
    for (int j = 0; j < 4; ++j) {
      const int   c  = j * 16 + cc;
      const float bb = b2[c];
#pragma unroll
      for (int i = 0; i < 4; ++i) {
        const int r = tile * 16 + (l >> 4) * 4 + i;
        msg[r * SH + c] = relu(acc[tile][j][i] + bb);
      }
    }
  }

  // ---- all-atomic segmented reduction over 32 rows
  {
    int   cur = __builtin_amdgcn_readlane(d, 0);
    float run = 0.f;
#pragma unroll
    for (int r = 0; r < 32; ++r) {
      float v  = msg[r * SH + l];
      int   dr = __builtin_amdgcn_readlane(d, r);
      if (r > 0 && dr != cur) {
        atomicAdd(new_states + (size_t)cur * DD + l, run);
        run = 0.f;
        cur = dr;
      }
      run += v;
    }
    atomicAdd(new_states + (size_t)cur * DD + l, run);
  }
}

// ===========================================================================
// atom_kernel_v2 (proven): readout MFMA + fp32 out + mol sum.
// ===========================================================================
__global__ __launch_bounds__(256, 4)
void atom_kernel_v2(const float* __restrict__ ns,
                    const unsigned short* __restrict__ whi,
                    const unsigned short* __restrict__ wlo,
                    const float* __restrict__ f1b,
                    const float* __restrict__ f2b,
                    const float* __restrict__ wo,
                    const float* __restrict__ bo,
                    float* __restrict__ out)
{
  __shared__ __align__(16) unsigned short Xb[2 * 64 * SH];
  __shared__ __align__(16) unsigned short Hb[2 * 64 * SH];
  unsigned short* Xh = Xb;
  unsigned short* Xl = Xb + 64 * SH;
  unsigned short* Hh = Hb;
  unsigned short* Hl = Hb + 64 * SH;
  float* h2f = (float*)Xb;
  float* oS  = (float*)Hb;

  const int t  = threadIdx.x;
  const int a0 = blockIdx.x * 64;

  {
    const int r  = t >> 2;
    const int k0 = (t & 3) * 16;
    const float4* s4 = (const float4*)(ns + (size_t)(a0 + r) * DD + k0);
#pragma unroll
    for (int f = 0; f < 4; ++f) {
      float4 v = s4[f];
      ushort4 h, lo;
      h.x = bfbits(v.x); lo.x = bfbits(v.x - bfval(h.x));
      h.y = bfbits(v.y); lo.y = bfbits(v.y - bfval(h.y));
      h.z = bfbits(v.z); lo.z = bfbits(v.z - bfval(h.z));
      h.w = bfbits(v.w); lo.w = bfbits(v.w - bfval(h.w));
      *(ushort4*)&Xh[r * SH + k0 + f * 4] = h;
      *(ushort4*)&Xl[r * SH + k0 + f * 4] = lo;
    }
  }

  const int l    = t & 63;
  const int w    = t >> 6;
  const int mrow = w * 16 + (l & 15);
  const int kq   = (l >> 4) * 8;
  const int cc   = l & 15;

  f32x4 acc[4];

#pragma unroll
  for (int j = 0; j < 4; ++j) acc[j] = (f32x4){0.f, 0.f, 0.f, 0.f};
#pragma unroll
  for (int s = 0; s < 2; ++s) {
    bf16x8 ah = ldfrag(&Xh[mrow * SH + s * 32 + kq]);
    bf16x8 al = ldfrag(&Xl[mrow * SH + s * 32 + kq]);
#pragma unroll
    for (int j = 0; j < 4; ++j) {
      const int fo = 4 * 4096 + ((j * 2 + s) * 64 + l) * 8;
      bf16x8 bh = ldfrag(whi + fo);
      bf16x8 bl = ldfrag(wlo + fo);
      acc[j] = mfma16(al, bh, acc[j]);
      acc[j] = mfma16(ah, bl, acc[j]);
      acc[j] = mfma16(ah, bh, acc[j]);
    }
  }
#pragma unroll
  for (int j = 0; j < 4; ++j) {
    const int   c  = j * 16 + cc;
    const float bb = f1b[c];
#pragma unroll
    for (int i = 0; i < 4; ++i) {
      const int r = w * 16 + (l >> 4) * 4 + i;
      float v = relu(acc[j][i] + bb);
      unsigned short hi = bfbits(v);
      Hh[r * SH + c] = hi;
      Hl[r * SH + c] = bfbits(v - bfval(hi));
    }
  }
  __syncthreads();

#pragma unroll
  for (int j = 0; j < 4; ++j) acc[j] = (f32x4){0.f, 0.f, 0.f, 0.f};
#pragma unroll
  for (int s = 0; s < 2; ++s) {
    bf16x8 ah = ldfrag(&Hh[mrow * SH + s * 32 + kq]);
    bf16x8 al = ldfrag(&Hl[mrow * SH + s * 32 + kq]);
#pragma unroll
    for (int j = 0; j < 4; ++j) {
      const int fo = 5 * 4096 + ((j * 2 + s) * 64 + l) * 8;
      bf16x8 bh = ldfrag(whi + fo);
      bf16x8 bl = ldfrag(wlo + fo);
      acc[j] = mfma16(al, bh, acc[j]);
      acc[j] = mfma16(ah, bl, acc[j]);
      acc[j] = mfma16(ah, bh, acc[j]);
    }
  }
#pragma unroll
  for (int j = 0; j < 4; ++j) {
    const int   c  = j * 16 + cc;
    const float bb = f2b[c];
#pragma unroll
    for (int i = 0; i < 4; ++i) {
      const int r = w * 16 + (l >> 4) * 4 + i;
      h2f[r * SH + c] = relu(acc[j][i] + bb);
    }
  }
  __syncthreads();

  {
    const int r  = t >> 2;
    const int c4 = (t & 3) * 4;
    float o4[4] = {0.f, 0.f, 0.f, 0.f};
#pragma unroll 8
    for (int k = 0; k < 64; ++k) {
      const float a = h2f[r * SH + k];
      float4 bw = *(const float4*)&wo[k * OUTD + c4];
      o4[0] += a * bw.x; o4[1] += a * bw.y; o4[2] += a * bw.z; o4[3] += a * bw.w;
    }
#pragma unroll
    for (int j = 0; j < 4; ++j)
      oS[r * 17 + c4 + j] = relu(o4[j] + bo[c4 + j]);
  }
  __syncthreads();

  if (t < 32) {
    const int m = t >> 4;
    const int c = t & 15;
    float s = 0.f;
#pragma unroll
    for (int a = 0; a < 32; ++a) s += oS[(m * 32 + a) * 17 + c];
    out[(blockIdx.x * 2 + m) * OUTD + c] = s;
  }
}

// ===========================================================================
extern "C" void kernel_launch(void* const* d_in, const int* in_sizes, int n_in,
                              void* d_out, int out_size, void* d_ws, size_t ws_size,
                              hipStream_t stream) {
  const float* atom_states = (const float*)d_in[0];
  const int*   edge_src    = (const int*)d_in[1];
  const int*   edge_dst    = (const int*)d_in[2];
  const float* ms0_w = (const float*)d_in[4];
  const float* ms0_b = (const float*)d_in[5];
  const float* ms1_w = (const float*)d_in[6];
  const float* ms1_b = (const float*)d_in[7];
  const float* ms2_w = (const float*)d_in[8];
  const float* ms2_b = (const float*)d_in[9];
  const float* fc1_w = (const float*)d_in[10];
  const float* fc1_b = (const float*)d_in[11];
  const float* fc2_w = (const float*)d_in[12];
  const float* fc2_b = (const float*)d_in[13];
  const float* out_w = (const float*)d_in[14];
  const float* out_b = (const float*)d_in[15];

  char* ws = (char*)d_ws;
  float* new_states = (float*)ws;
  size_t off = (size_t)N_ATOMS * DD * sizeof(float);                    // 32 MiB
  int* cnt     = (int*)(ws + off); off += (size_t)N_ATOMS * 4;          // +512 KiB
  int* cursor  = (int*)(ws + off); off += (size_t)N_ATOMS * 4;          // +512 KiB
  int* partial = (int*)(ws + off); off += 4096;                         // B-path
  int* flags   = (int*)(ws + off); off += 4096;  // [0]=ovf_cnt [1]=gbase
  unsigned short* whi = (unsigned short*)(ws + off); off += 24576 * 2;
  unsigned short* wlo = (unsigned short*)(ws + off); off += 24576 * 2;
  float* Yd = (float*)(ws + off); off += (size_t)N_ATOMS * DD * sizeof(float);
  float* Ys = (float*)(ws + off); off += (size_t)N_ATOMS * DD * sizeof(float);
  int2* ds_sorted = (int2*)(ws + off); off += (size_t)N_EDGES * 8;      // +8 MiB
  const size_t needB = off;                                             // ~105 MiB
  int* bucket = (int*)(ws + off); off += (size_t)N_ATOMS * BCAP * 4;    // +8 MiB
  const size_t needC = off;                                             // ~113 MiB

  const int useC = (ws_size >= needC) ? 1 : 0;   // constant across calls

  int* ovf_cnt = flags;
  int* gbase   = flags + 1;

  k0_pack_zero<<<140, 256, 0, stream>>>(ms0_w, ms1_w, ms2_w, fc1_w, fc2_w,
                                        whi, wlo, cnt, flags);

  if (useC) {
    k1_bucket_pre<<<6144, 256, 0, stream>>>(atom_states, edge_src, edge_dst,
                                            cnt, bucket, ds_sorted, ovf_cnt,
                                            whi, wlo, ms0_b, Yd, Ys, new_states);
    scan_compact_atomic<<<512, 256, 0, stream>>>(cnt, gbase, bucket, ds_sorted);
  } else {
    k1_hist<<<4096, 256, 0, stream>>>(edge_dst, cnt);
    blocksum_kernel<<<512, 256, 0, stream>>>(cnt, partial, 0x7fffffff);
    scanwrite_kernel<<<512, 256, 0, stream>>>(cnt, partial, cursor, 0x7fffffff);
    k2_scatter_pre<<<6144, 256, 0, stream>>>(atom_states, edge_src, edge_dst,
                                             cursor, ds_sorted,
                                             whi, wlo, ms0_b, Yd, Ys, new_states);
  }

  edge_kernel_v10<<<N_EDGES / 128, 256, 0, stream>>>(
      Yd, Ys, ds_sorted, whi, wlo, ms1_b, ms2_b, new_states);

  atom_kernel_v2<<<N_ATOMS / 64, 256, 0, stream>>>(
      new_states, whi, wlo, fc1_b, fc2_b, out_w, out_b, (float*)d_out);
}